// Round 7
// baseline (20743.195 us; speedup 1.0000x reference)
//
#include <hip/hip_runtime.h>

#define B_   64
#define T_   256
#define H_   512
#define F0_  256
#define C_   32
#define TC   16
#define NCOLS (TC*64)   // 1024

typedef short short8 __attribute__((ext_vector_type(8)));
typedef float f32x4 __attribute__((ext_vector_type(4)));

__device__ __forceinline__ float aload(const float* p) {
    return __hip_atomic_load(p, __ATOMIC_RELAXED, __HIP_MEMORY_SCOPE_AGENT);
}
__device__ __forceinline__ void astore(float* p, float v) {
    __hip_atomic_store(p, v, __ATOMIC_RELAXED, __HIP_MEMORY_SCOPE_AGENT);
}
__device__ __forceinline__ unsigned aload_u32(const unsigned* p) {
    return __hip_atomic_load(p, __ATOMIC_RELAXED, __HIP_MEMORY_SCOPE_AGENT);
}
__device__ __forceinline__ void astore_u32(unsigned* p, unsigned v) {
    __hip_atomic_store(p, v, __ATOMIC_RELAXED, __HIP_MEMORY_SCOPE_AGENT);
}

// split f32 -> (bf16 hi | bf16 lo) packed in u32 (hi in top 16, lo in bottom 16)
__device__ __forceinline__ unsigned pack_split(float x) {
    unsigned xb = __float_as_uint(x);
    unsigned hi = (xb + 0x7fffu + ((xb >> 16) & 1u)) & 0xffff0000u;
    float rest = x - __uint_as_float(hi);
    unsigned rb = __float_as_uint(rest);
    unsigned lo = (rb + 0x7fffu + ((rb >> 16) & 1u)) >> 16;
    return hi | (lo & 0xffffu);
}

// ---------------- f32 GEMM: pre(4096, NCOLS) = Wih * B^T + bias, 128x128 tile ---
__global__ __launch_bounds__(256) void gemm_f32(
    const float* __restrict__ A, const float* __restrict__ Bsrc,
    const float* __restrict__ bias, float* __restrict__ C,
    int K, int mode, int lo)
{
    __shared__ __align__(16) float As[16][132];
    __shared__ __align__(16) float Bs[16][132];
    const int m0 = blockIdx.y * 128;
    const int n0 = blockIdx.x * 128;
    const int dir = m0 >> 11;
    const int tid = threadIdx.x;
    const int tx = tid & 15, ty = tid >> 4;

    float acc[8][8];
#pragma unroll
    for (int i = 0; i < 8; ++i)
#pragma unroll
        for (int j = 0; j < 8; ++j) acc[i][j] = 0.f;

    for (int k0 = 0; k0 < K; k0 += 16) {
        __syncthreads();
        {
            int row = tid >> 1;
            int cof = (tid & 1) * 8;
            const float* ap = A + (size_t)(m0 + row) * K + k0 + cof;
            float4 v0 = *(const float4*)ap;
            float4 v1 = *(const float4*)(ap + 4);
            As[cof+0][row]=v0.x; As[cof+1][row]=v0.y; As[cof+2][row]=v0.z; As[cof+3][row]=v0.w;
            As[cof+4][row]=v1.x; As[cof+5][row]=v1.y; As[cof+6][row]=v1.z; As[cof+7][row]=v1.w;
        }
        if (mode == 0) {
            int nn = tid >> 1;
            int cof = (tid & 1) * 8;
            int n = n0 + nn;
            int bb = n & 63, tloc = n >> 6;
            int t = dir ? (255 - lo - tloc) : (lo + tloc);
            const float* bp = Bsrc + ((size_t)bb * T_ + t) * F0_ + k0 + cof;
            float4 v0 = *(const float4*)bp;
            float4 v1 = *(const float4*)(bp + 4);
            Bs[cof+0][nn]=v0.x; Bs[cof+1][nn]=v0.y; Bs[cof+2][nn]=v0.z; Bs[cof+3][nn]=v0.w;
            Bs[cof+4][nn]=v1.x; Bs[cof+5][nn]=v1.y; Bs[cof+6][nn]=v1.z; Bs[cof+7][nn]=v1.w;
        } else {
            int kk = tid >> 4;
            int nn = (tid & 15) * 8;
            int n = n0 + nn;
            int tloc = n >> 6, bb = n & 63;
            int t = dir ? (255 - lo - tloc) : (lo + tloc);
            const float* bp = Bsrc + (size_t)t * (1024*64) + (size_t)(k0+kk)*64 + bb;
            float4 v0 = *(const float4*)bp;
            float4 v1 = *(const float4*)(bp + 4);
            *(float4*)&Bs[kk][nn]   = v0;
            *(float4*)&Bs[kk][nn+4] = v1;
        }
        __syncthreads();
#pragma unroll
        for (int kk = 0; kk < 16; ++kk) {
            float4 a0 = *(const float4*)&As[kk][ty*4];
            float4 a1 = *(const float4*)&As[kk][ty*4+64];
            float4 b0 = *(const float4*)&Bs[kk][tx*4];
            float4 b1 = *(const float4*)&Bs[kk][tx*4+64];
            float af[8] = {a0.x,a0.y,a0.z,a0.w,a1.x,a1.y,a1.z,a1.w};
            float bf[8] = {b0.x,b0.y,b0.z,b0.w,b1.x,b1.y,b1.z,b1.w};
#pragma unroll
            for (int i = 0; i < 8; ++i)
#pragma unroll
                for (int j = 0; j < 8; ++j) acc[i][j] += af[i]*bf[j];
        }
    }
#pragma unroll
    for (int i = 0; i < 8; ++i) {
        int ml = (i < 4) ? (ty*4 + i) : (64 + ty*4 + (i-4));
        int m = m0 + ml;
        float bv = bias[m];
        float4 o0, o1;
        o0.x = acc[i][0]+bv; o0.y = acc[i][1]+bv; o0.z = acc[i][2]+bv; o0.w = acc[i][3]+bv;
        o1.x = acc[i][4]+bv; o1.y = acc[i][5]+bv; o1.z = acc[i][6]+bv; o1.w = acc[i][7]+bv;
        *(float4*)&C[(size_t)m*NCOLS + n0 + tx*4]      = o0;
        *(float4*)&C[(size_t)m*NCOLS + n0 + 64 + tx*4] = o1;
    }
}

// ---------------- persistent bidirectional LSTM scan, MFMA split-bf16 ----------
// 256 blocks = 2 dir x 128 kblk (4 k each). 512 threads = 8 waves.
// Waves 0-3: mfma over n-tiles (16 b each). All waves: stage h into LDS.
// LDS (160 KiB exact): W hi/lo bf16 [16 m][512 j] (32K) + B hi/lo bf16 [64 b][512 j] (128K).
// h published as packed split-bf16 u32 via relaxed agent atomics (L3); grid barrier =
// 8 distributed relaxed counters. Gate rows arranged m = kl*4+g so each mfma lane
// holds all 4 gates of one (k,b): activations + c fully in-lane (C layout m89).
#define LDS_W_HI 0
#define LDS_W_LO 16384
#define LDS_B_HI 32768
#define LDS_B_LO 98304

__global__ __launch_bounds__(512, 1) void lstm_scan(
    const float* __restrict__ Whh,   // (2, 2048, 512)
    const float* __restrict__ pre,   // (4096, NCOLS)
    float* __restrict__ out,         // (T_, 1024, B_)
    unsigned* __restrict__ hpk,      // [2 par][2 dir][64 b][512 k] packed u32
    float* __restrict__ cbuf,        // [2 dir][512 k][64 b]
    unsigned* bar,
    int lo, int first, unsigned tgt0)
{
    extern __shared__ char smem[];
    const int bid  = blockIdx.x;
    const int dir  = bid >> 7;
    const int kblk = bid & 127;
    const int tid  = threadIdx.x;
    const int wid  = tid >> 6;
    const int lane = tid & 63;
    const int dlt  = lane & 15;      // delta: m (A) / b-col (B/C)
    const int gma  = lane >> 4;      // gamma: k-group

    // ---- W prep (once): global row dir*2048 + g*512 + kblk*4 + kl  -> m = kl*4+g
    {
        const int m  = tid >> 5;          // 0..15
        const int j0 = (tid & 31) * 16;   // element
        const int g = m & 3, kl = m >> 2;
        const float* wr = Whh + ((size_t)(dir*2048 + g*512 + kblk*4 + kl))*512 + j0;
        unsigned hw[8], lw[8];
#pragma unroll
        for (int i = 0; i < 8; ++i) {
            unsigned q0 = pack_split(wr[2*i]);
            unsigned q1 = pack_split(wr[2*i+1]);
            hw[i] = (q0 >> 16) | (q1 & 0xffff0000u);
            lw[i] = (q0 & 0xffffu) | (q1 << 16);
        }
        const int jb = j0 * 2;
        const int of0 = (m << 10) + ((jb     ) ^ ((m & 7) << 4));
        const int of1 = (m << 10) + ((jb + 16) ^ ((m & 7) << 4));
        *(uint4*)(smem + LDS_W_HI + of0) = make_uint4(hw[0],hw[1],hw[2],hw[3]);
        *(uint4*)(smem + LDS_W_HI + of1) = make_uint4(hw[4],hw[5],hw[6],hw[7]);
        *(uint4*)(smem + LDS_W_LO + of0) = make_uint4(lw[0],lw[1],lw[2],lw[3]);
        *(uint4*)(smem + LDS_W_LO + of1) = make_uint4(lw[4],lw[5],lw[6],lw[7]);
    }

    unsigned* hp0 = hpk + (size_t)(0*2 + dir) * 32768;
    unsigned* hp1 = hpk + (size_t)(1*2 + dir) * 32768;

    const int kg = kblk*4 + gma;          // global k   (mfma waves)
    const int bb = wid*16 + dlt;          // batch b    (mfma waves, wid<4)

    float c = 0.f;
    if (first) {
        for (int i = tid; i < 32768; i += 512) astore_u32(&hp1[i], 0u);
    } else if (wid < 4) {
        c = cbuf[(size_t)dir*32768 + (size_t)kg*64 + bb];
    }
    asm volatile("s_waitcnt vmcnt(0)" ::: "memory");
    __syncthreads();

    const int sb = tid >> 3;              // staging: b 0..63
    const int sj = (tid & 7) * 64;        // staging: j start (elements)
    const int mycnt = (bid & 7) * 32;
    unsigned target = tgt0;

    for (int s = 0; s < TC; ++s) {
        const int u = lo + s;
        const int t = dir ? (255 - u) : u;

        float p0, p1, p2, p3;
        if (wid < 4) {   // issue pre loads early; hidden under barrier wait
            const size_t col = (size_t)s*64 + bb;
            p0 = pre[((size_t)(dir*2048 +        kg))*NCOLS + col];
            p1 = pre[((size_t)(dir*2048 +  512 + kg))*NCOLS + col];
            p2 = pre[((size_t)(dir*2048 + 1024 + kg))*NCOLS + col];
            p3 = pre[((size_t)(dir*2048 + 1536 + kg))*NCOLS + col];
        }

        // ---- grid barrier (relaxed, distributed) ----
        if (tid == 0)
            __hip_atomic_fetch_add(&bar[mycnt], 1u, __ATOMIC_RELAXED, __HIP_MEMORY_SCOPE_AGENT);
        target += 32;
        if (tid < 8) {
            while (__hip_atomic_load(&bar[tid*32], __ATOMIC_RELAXED, __HIP_MEMORY_SCOPE_AGENT) < target)
                __builtin_amdgcn_s_sleep(2);
        }
        __syncthreads();

        // ---- stage h_{u-1}: 64 packed u32 / thread -> split bf16 LDS ----
        const unsigned* src = ((u + 1) & 1) ? hp1 : hp0;
        const unsigned* srow = src + (size_t)sb*512 + sj;
#pragma unroll
        for (int gq = 0; gq < 4; ++gq) {
            unsigned v[16];
#pragma unroll
            for (int i = 0; i < 16; ++i) v[i] = aload_u32(&srow[gq*16 + i]);
            unsigned hw[8], lw[8];
#pragma unroll
            for (int i = 0; i < 8; ++i) {
                hw[i] = (v[2*i] >> 16) | (v[2*i+1] & 0xffff0000u);
                lw[i] = (v[2*i] & 0xffffu) | (v[2*i+1] << 16);
            }
            const int jb = sj*2 + gq*32;
            const int o0 = (sb<<10) + ((jb     ) ^ ((sb&7)<<4) ^ ((((jb     )>>8)&7)<<4));
            const int o1 = (sb<<10) + ((jb + 16) ^ ((sb&7)<<4) ^ ((((jb + 16)>>8)&7)<<4));
            *(uint4*)(smem + LDS_B_HI + o0) = make_uint4(hw[0],hw[1],hw[2],hw[3]);
            *(uint4*)(smem + LDS_B_HI + o1) = make_uint4(hw[4],hw[5],hw[6],hw[7]);
            *(uint4*)(smem + LDS_B_LO + o0) = make_uint4(lw[0],lw[1],lw[2],lw[3]);
            *(uint4*)(smem + LDS_B_LO + o1) = make_uint4(lw[4],lw[5],lw[6],lw[7]);
        }
        __syncthreads();

        // ---- mfma K-loop + epilogue (waves 0-3) ----
        if (wid < 4) {
            f32x4 acc = {p0, p1, p2, p3};
#pragma unroll
            for (int kt = 0; kt < 16; ++kt) {
                const int jb  = (kt << 6) + (gma << 4);
                const int aof = (dlt << 10) + (jb ^ ((dlt & 7) << 4));
                const int bof = (bb  << 10) + (jb ^ ((dlt & 7) << 4) ^ (((kt >> 2) & 7) << 4));
                short8 ah = *(const short8*)(smem + LDS_W_HI + aof);
                short8 al = *(const short8*)(smem + LDS_W_LO + aof);
                short8 bh = *(const short8*)(smem + LDS_B_HI + bof);
                short8 bl = *(const short8*)(smem + LDS_B_LO + bof);
                acc = __builtin_amdgcn_mfma_f32_16x16x32_bf16(ah, bh, acc, 0, 0, 0);
                acc = __builtin_amdgcn_mfma_f32_16x16x32_bf16(ah, bl, acc, 0, 0, 0);
                acc = __builtin_amdgcn_mfma_f32_16x16x32_bf16(al, bh, acc, 0, 0, 0);
                acc = __builtin_amdgcn_mfma_f32_16x16x32_bf16(al, bl, acc, 0, 0, 0);
            }
            float ig = 1.f / (1.f + expf(-acc[0]));
            float fg = 1.f / (1.f + expf(-acc[1]));
            float gg = tanhf(acc[2]);
            float og = 1.f / (1.f + expf(-acc[3]));
            c = fg * c + ig * gg;
            float h = og * tanhf(c);
            out[((size_t)t*1024 + dir*512 + kg)*64 + bb] = h;
            astore_u32(((u & 1) ? hp1 : hp0) + (size_t)bb*512 + kg, pack_split(h));
            if (s == TC-1) cbuf[(size_t)dir*32768 + (size_t)kg*64 + bb] = c;
            asm volatile("s_waitcnt vmcnt(0)" ::: "memory");
        }
        __syncthreads();   // publishes drained before any wave re-arrives
    }
}

// ---------------- emissions -----------------------------------------------------
__global__ __launch_bounds__(256) void emis_kernel(
    const float* __restrict__ h1, const float* __restrict__ Wout,
    const float* __restrict__ bout, float* __restrict__ em)
{
    const int s = blockIdx.x;
    const int tid = threadIdx.x;
    const int b = tid & 63;
    const int cl = tid >> 6;
    __shared__ float wl[32][128];
    float acc[8];
#pragma unroll
    for (int u = 0; u < 8; ++u) acc[u] = 0.f;
    const float* hp = h1 + (size_t)s * (1024*64);
    for (int f0 = 0; f0 < 1024; f0 += 128) {
        __syncthreads();
        for (int u = tid; u < 4096; u += 256) {
            int cc = u >> 7, ff = u & 127;
            wl[cc][ff] = Wout[(size_t)cc*1024 + f0 + ff];
        }
        __syncthreads();
        for (int ff = 0; ff < 128; ++ff) {
            float hv = hp[(size_t)(f0+ff)*64 + b];
#pragma unroll
            for (int u = 0; u < 8; ++u) acc[u] += hv * wl[cl + u*4][ff];
        }
    }
#pragma unroll
    for (int u = 0; u < 8; ++u) {
        int cc = cl + u*4;
        em[((size_t)b*T_ + s)*C_ + cc] = acc[u] + bout[cc];
    }
}

// ---------------- CRF Viterbi ---------------------------------------------------
__global__ __launch_bounds__(64) void viterbi_kernel(
    const float* __restrict__ em, const float* __restrict__ start_t,
    const float* __restrict__ end_t, const float* __restrict__ trans,
    float* __restrict__ dout)
{
    const int b = blockIdx.x;
    const int j = threadIdx.x;
    __shared__ float tr[C_*C_];
    __shared__ float sc[2][C_];
    __shared__ unsigned char hist[T_-1][C_];
    for (int i = j; i < C_*C_; i += 64) tr[i] = trans[i];
    const float* emb = em + (size_t)b * T_ * C_;
    if (j < C_) sc[0][j] = start_t[j] + emb[j];
    __syncthreads();
    for (int s = 1; s < T_; ++s) {
        int cur = (s-1) & 1, nxt = s & 1;
        if (j < C_) {
            float best = -3.4e38f; int bi = 0;
            for (int i = 0; i < C_; ++i) {
                float v = sc[cur][i] + tr[i*C_ + j];
                if (v > best) { best = v; bi = i; }
            }
            sc[nxt][j] = best + emb[(size_t)s*C_ + j];
            hist[s-1][j] = (unsigned char)bi;
        }
        __syncthreads();
    }
    if (j == 0) {
        const int cur = (T_-1) & 1;
        float best = -3.4e38f; int bi = 0;
        for (int i = 0; i < C_; ++i) {
            float v = sc[cur][i] + end_t[i];
            if (v > best) { best = v; bi = i; }
        }
        dout[(size_t)B_*T_ + b] = best;
        float* tout = dout + (size_t)b * T_;
        int tag = bi;
        tout[T_-1] = (float)tag;
        for (int s = T_-2; s >= 0; --s) {
            tag = hist[s][tag];
            tout[s] = (float)tag;
        }
    }
}

// ---------------- host launch ---------------------------------------------------
extern "C" void kernel_launch(void* const* d_in, const int* in_sizes, int n_in,
                              void* d_out, int out_size, void* d_ws, size_t ws_size,
                              hipStream_t stream) {
    const float* x    = (const float*)d_in[0];
    const float* Wih0 = (const float*)d_in[2];
    const float* Whh0 = (const float*)d_in[3];
    const float* b0   = (const float*)d_in[4];
    const float* Wih1 = (const float*)d_in[5];
    const float* Whh1 = (const float*)d_in[6];
    const float* b1   = (const float*)d_in[7];
    const float* Wout = (const float*)d_in[8];
    const float* bout = (const float*)d_in[9];
    const float* st   = (const float*)d_in[10];
    const float* en   = (const float*)d_in[11];
    const float* tr   = (const float*)d_in[12];
    float* dout = (float*)d_out;

    char* ws = (char*)d_ws;
    unsigned* bar  = (unsigned*)ws;                               // 4 KiB (8 ctrs, 128B apart)
    unsigned* hpk  = (unsigned*)(ws + 4096);                      // 512 KiB packed h
    float* cbuf = (float*)(ws + 4096 + 524288);                   // 256 KiB
    float* em   = (float*)(ws + 4096 + (1u << 20));               // 2 MiB
    float* h0   = (float*)(ws + 4096 + (1u << 20) + (2u << 20));  // 64 MiB
    float* h1   = h0 + (size_t)T_ * 1024 * B_;                    // 64 MiB
    float* pre  = h1 + (size_t)T_ * 1024 * B_;                    // 16.8 MiB

    hipMemsetAsync(bar, 0, 4096, stream);

    const int LDS_BYTES = 163840;   // 32K W split + 128K B split
    hipFuncSetAttribute(reinterpret_cast<const void*>(lstm_scan),
                        hipFuncAttributeMaxDynamicSharedMemorySize, LDS_BYTES);

    dim3 bb(256);
    dim3 gg(NCOLS/128, 32);
    for (int ci = 0; ci < 16; ++ci) {
        int lo = ci * TC;
        gemm_f32<<<gg, bb, 0, stream>>>(Wih0, x, b0, pre, F0_, 0, lo);
        lstm_scan<<<256, 512, LDS_BYTES, stream>>>(Whh0, pre, h0, hpk, cbuf, bar,
                                                   lo, ci == 0 ? 1 : 0, (unsigned)(ci * TC * 32));
    }
    for (int ci = 0; ci < 16; ++ci) {
        int lo = ci * TC;
        gemm_f32<<<gg, bb, 0, stream>>>(Wih1, h0, b1, pre, 1024, 1, lo);
        lstm_scan<<<256, 512, LDS_BYTES, stream>>>(Whh1, pre, h1, hpk, cbuf, bar,
                                                   lo, ci == 0 ? 1 : 0, (unsigned)((16 + ci) * TC * 32));
    }
    emis_kernel<<<T_, bb, 0, stream>>>(h1, Wout, bout, em);
    viterbi_kernel<<<B_, 64, 0, stream>>>(em, st, en, tr, dout);
}

// Round 8
// 9396.331 us; speedup vs baseline: 2.2076x; 2.2076x over previous
//
#include <hip/hip_runtime.h>

#define B_   64
#define T_   256
#define H_   512
#define F0_  256
#define C_   32
#define TC   16
#define NCOLS (TC*64)   // 1024

typedef short short8 __attribute__((ext_vector_type(8)));
typedef float f32x4 __attribute__((ext_vector_type(4)));
typedef unsigned long long u64;

__device__ __forceinline__ unsigned aload_u32(const unsigned* p) {
    return __hip_atomic_load(p, __ATOMIC_RELAXED, __HIP_MEMORY_SCOPE_AGENT);
}
__device__ __forceinline__ void astore_u32(unsigned* p, unsigned v) {
    __hip_atomic_store(p, v, __ATOMIC_RELAXED, __HIP_MEMORY_SCOPE_AGENT);
}
__device__ __forceinline__ u64 aload_u64(const u64* p) {
    return __hip_atomic_load(p, __ATOMIC_RELAXED, __HIP_MEMORY_SCOPE_AGENT);
}

// split f32 -> (bf16 hi | bf16 lo) packed in u32 (hi in top 16, lo in bottom 16)
__device__ __forceinline__ unsigned pack_split(float x) {
    unsigned xb = __float_as_uint(x);
    unsigned hi = (xb + 0x7fffu + ((xb >> 16) & 1u)) & 0xffff0000u;
    float rest = x - __uint_as_float(hi);
    unsigned rb = __float_as_uint(rest);
    unsigned lo = (rb + 0x7fffu + ((rb >> 16) & 1u)) >> 16;
    return hi | (lo & 0xffffu);
}

// ---------------- f32 GEMM: pre(4096, NCOLS) = Wih * B^T + bias, 128x128 tile ---
__global__ __launch_bounds__(256) void gemm_f32(
    const float* __restrict__ A, const float* __restrict__ Bsrc,
    const float* __restrict__ bias, float* __restrict__ C,
    int K, int mode, int lo)
{
    __shared__ __align__(16) float As[16][132];
    __shared__ __align__(16) float Bs[16][132];
    const int m0 = blockIdx.y * 128;
    const int n0 = blockIdx.x * 128;
    const int dir = m0 >> 11;
    const int tid = threadIdx.x;
    const int tx = tid & 15, ty = tid >> 4;

    float acc[8][8];
#pragma unroll
    for (int i = 0; i < 8; ++i)
#pragma unroll
        for (int j = 0; j < 8; ++j) acc[i][j] = 0.f;

    for (int k0 = 0; k0 < K; k0 += 16) {
        __syncthreads();
        {
            int row = tid >> 1;
            int cof = (tid & 1) * 8;
            const float* ap = A + (size_t)(m0 + row) * K + k0 + cof;
            float4 v0 = *(const float4*)ap;
            float4 v1 = *(const float4*)(ap + 4);
            As[cof+0][row]=v0.x; As[cof+1][row]=v0.y; As[cof+2][row]=v0.z; As[cof+3][row]=v0.w;
            As[cof+4][row]=v1.x; As[cof+5][row]=v1.y; As[cof+6][row]=v1.z; As[cof+7][row]=v1.w;
        }
        if (mode == 0) {
            int nn = tid >> 1;
            int cof = (tid & 1) * 8;
            int n = n0 + nn;
            int bb = n & 63, tloc = n >> 6;
            int t = dir ? (255 - lo - tloc) : (lo + tloc);
            const float* bp = Bsrc + ((size_t)bb * T_ + t) * F0_ + k0 + cof;
            float4 v0 = *(const float4*)bp;
            float4 v1 = *(const float4*)(bp + 4);
            Bs[cof+0][nn]=v0.x; Bs[cof+1][nn]=v0.y; Bs[cof+2][nn]=v0.z; Bs[cof+3][nn]=v0.w;
            Bs[cof+4][nn]=v1.x; Bs[cof+5][nn]=v1.y; Bs[cof+6][nn]=v1.z; Bs[cof+7][nn]=v1.w;
        } else {
            int kk = tid >> 4;
            int nn = (tid & 15) * 8;
            int n = n0 + nn;
            int tloc = n >> 6, bb = n & 63;
            int t = dir ? (255 - lo - tloc) : (lo + tloc);
            const float* bp = Bsrc + (size_t)t * (1024*64) + (size_t)(k0+kk)*64 + bb;
            float4 v0 = *(const float4*)bp;
            float4 v1 = *(const float4*)(bp + 4);
            *(float4*)&Bs[kk][nn]   = v0;
            *(float4*)&Bs[kk][nn+4] = v1;
        }
        __syncthreads();
#pragma unroll
        for (int kk = 0; kk < 16; ++kk) {
            float4 a0 = *(const float4*)&As[kk][ty*4];
            float4 a1 = *(const float4*)&As[kk][ty*4+64];
            float4 b0 = *(const float4*)&Bs[kk][tx*4];
            float4 b1 = *(const float4*)&Bs[kk][tx*4+64];
            float af[8] = {a0.x,a0.y,a0.z,a0.w,a1.x,a1.y,a1.z,a1.w};
            float bf[8] = {b0.x,b0.y,b0.z,b0.w,b1.x,b1.y,b1.z,b1.w};
#pragma unroll
            for (int i = 0; i < 8; ++i)
#pragma unroll
                for (int j = 0; j < 8; ++j) acc[i][j] += af[i]*bf[j];
        }
    }
#pragma unroll
    for (int i = 0; i < 8; ++i) {
        int ml = (i < 4) ? (ty*4 + i) : (64 + ty*4 + (i-4));
        int m = m0 + ml;
        float bv = bias[m];
        float4 o0, o1;
        o0.x = acc[i][0]+bv; o0.y = acc[i][1]+bv; o0.z = acc[i][2]+bv; o0.w = acc[i][3]+bv;
        o1.x = acc[i][4]+bv; o1.y = acc[i][5]+bv; o1.z = acc[i][6]+bv; o1.w = acc[i][7]+bv;
        *(float4*)&C[(size_t)m*NCOLS + n0 + tx*4]      = o0;
        *(float4*)&C[(size_t)m*NCOLS + n0 + 64 + tx*4] = o1;
    }
}

// ---------------- persistent bidirectional LSTM scan, MFMA split-bf16 ----------
// 256 blocks = 2 dir x 128 kblk (4 k each). 512 threads = 8 waves; waves 0-3 mfma.
// LDS 160K: W split bf16 hi/lo [16 m][512 j] (32K) + B packed u32, chunk-swizzled
//   [jc 0..127][slot = b ^ (jc&7)] of 16B chunks (128K).
// Staging = pure coalesced copy (u64 agent-atomic load, unit-stride across lanes
// -> 512B L3 bursts; ds_write_b64 at floor rate). mfma unpacks hi/lo in-register.
#define LDS_W_HI 0
#define LDS_W_LO 16384
#define LDS_B    32768

__global__ __launch_bounds__(512, 1) void lstm_scan(
    const float* __restrict__ Whh,   // (2, 2048, 512)
    const float* __restrict__ pre,   // (4096, NCOLS)
    float* __restrict__ out,         // (T_, 1024, B_)
    unsigned* __restrict__ hpk,      // [2 par][2 dir][64 b][512 k] packed u32
    float* __restrict__ cbuf,        // [2 dir][512 k][64 b]
    unsigned* bar,
    int lo, int first, unsigned tgt0)
{
    extern __shared__ char smem[];
    const int bid  = blockIdx.x;
    const int dir  = bid >> 7;
    const int kblk = bid & 127;
    const int tid  = threadIdx.x;
    const int wid  = tid >> 6;
    const int lane = tid & 63;
    const int dlt  = lane & 15;      // n-col (b within wave tile) / A m-row
    const int gma  = lane >> 4;      // K-group / C row-group

    // ---- W prep (once): A row m = kl*4+g  <- W row dir*2048 + g*512 + kblk*4+kl
    {
        const int m  = tid >> 5;          // 0..15
        const int j0 = (tid & 31) * 16;   // element
        const int g = m & 3, kl = m >> 2;
        const float* wr = Whh + ((size_t)(dir*2048 + g*512 + kblk*4 + kl))*512 + j0;
        unsigned hw[8], lw[8];
#pragma unroll
        for (int i = 0; i < 8; ++i) {
            unsigned q0 = pack_split(wr[2*i]);
            unsigned q1 = pack_split(wr[2*i+1]);
            hw[i] = (q0 >> 16) | (q1 & 0xffff0000u);
            lw[i] = (q0 & 0xffffu) | (q1 << 16);
        }
        const int jb = j0 * 2;
        const int of0 = (m << 10) + ((jb     ) ^ ((m & 7) << 4));
        const int of1 = (m << 10) + ((jb + 16) ^ ((m & 7) << 4));
        *(uint4*)(smem + LDS_W_HI + of0) = make_uint4(hw[0],hw[1],hw[2],hw[3]);
        *(uint4*)(smem + LDS_W_HI + of1) = make_uint4(hw[4],hw[5],hw[6],hw[7]);
        *(uint4*)(smem + LDS_W_LO + of0) = make_uint4(lw[0],lw[1],lw[2],lw[3]);
        *(uint4*)(smem + LDS_W_LO + of1) = make_uint4(lw[4],lw[5],lw[6],lw[7]);
    }

    unsigned* hp0 = hpk + (size_t)(0*2 + dir) * 32768;
    unsigned* hp1 = hpk + (size_t)(1*2 + dir) * 32768;

    const int kg = kblk*4 + gma;          // this lane's k   (mfma waves)
    const int bb = wid*16 + dlt;          // this lane's b   (mfma waves, wid<4)

    float c = 0.f;
    if (first) {
        for (int i = tid; i < 32768; i += 512) astore_u32(&hp1[i], 0u);
    } else if (wid < 4) {
        c = cbuf[(size_t)dir*32768 + (size_t)kg*64 + bb];
    }
    asm volatile("s_waitcnt vmcnt(0)" ::: "memory");
    __syncthreads();

    const int mycnt = (bid & 7) * 32;
    unsigned target = tgt0;
    // loop-invariant B chunk bases: jc0 = 8kt+2gma -> (jc&7) = 2gma (const)
    const int bof0 = (2*gma)*1024 + ((bb ^ (2*gma)) << 4);
    const int bof1 = (2*gma+1)*1024 + ((bb ^ (2*gma+1)) << 4);

    for (int s = 0; s < TC; ++s) {
        const int u = lo + s;
        const int t = dir ? (255 - u) : u;

        float p0, p1, p2, p3;
        if (wid < 4) {   // issue pre loads early; hidden under barrier wait
            const size_t col = (size_t)s*64 + bb;
            p0 = pre[((size_t)(dir*2048 +        kg))*NCOLS + col];
            p1 = pre[((size_t)(dir*2048 +  512 + kg))*NCOLS + col];
            p2 = pre[((size_t)(dir*2048 + 1024 + kg))*NCOLS + col];
            p3 = pre[((size_t)(dir*2048 + 1536 + kg))*NCOLS + col];
        }

        // ---- grid barrier (relaxed, distributed) ----
        if (tid == 0)
            __hip_atomic_fetch_add(&bar[mycnt], 1u, __ATOMIC_RELAXED, __HIP_MEMORY_SCOPE_AGENT);
        target += 32;
        if (tid < 8) {
            while (__hip_atomic_load(&bar[tid*32], __ATOMIC_RELAXED, __HIP_MEMORY_SCOPE_AGENT) < target)
                __builtin_amdgcn_s_sleep(2);
        }
        __syncthreads();

        // ---- stage h_{u-1}: coalesced u64 copy -> chunk-swizzled LDS ----
        const u64* src64 = (const u64*)(((u + 1) & 1) ? hp1 : hp0);
#pragma unroll 8
        for (int it = 0; it < 32; ++it) {
            const int idx = it*512 + tid;          // u64 index
            u64 v = aload_u64(&src64[idx]);
            const int b  = idx >> 8;
            const int j2 = idx & 255;
            const int jc = j2 >> 1;
            const int byte = ((jc*64 + (b ^ (jc & 7))) << 4) + ((j2 & 1) << 3);
            *(u64*)(smem + LDS_B + byte) = v;
        }
        __syncthreads();

        // ---- mfma K-loop + epilogue (waves 0-3) ----
        if (wid < 4) {
            f32x4 acc = {p0, p1, p2, p3};
#pragma unroll
            for (int kt = 0; kt < 16; ++kt) {
                const int jb  = (kt << 6) + (gma << 4);
                const int aof = (dlt << 10) + (jb ^ ((dlt & 7) << 4));
                short8 ah = *(const short8*)(smem + LDS_W_HI + aof);
                short8 al = *(const short8*)(smem + LDS_W_LO + aof);
                uint4 u0 = *(const uint4*)(smem + LDS_B + bof0 + (kt << 13));
                uint4 u1 = *(const uint4*)(smem + LDS_B + bof1 + (kt << 13));
                union { uint4 u; short8 s; } bh, bl;
                bh.u = make_uint4((u0.x >> 16) | (u0.y & 0xffff0000u),
                                  (u0.z >> 16) | (u0.w & 0xffff0000u),
                                  (u1.x >> 16) | (u1.y & 0xffff0000u),
                                  (u1.z >> 16) | (u1.w & 0xffff0000u));
                bl.u = make_uint4((u0.x & 0xffffu) | (u0.y << 16),
                                  (u0.z & 0xffffu) | (u0.w << 16),
                                  (u1.x & 0xffffu) | (u1.y << 16),
                                  (u1.z & 0xffffu) | (u1.w << 16));
                acc = __builtin_amdgcn_mfma_f32_16x16x32_bf16(ah, bh.s, acc, 0, 0, 0);
                acc = __builtin_amdgcn_mfma_f32_16x16x32_bf16(ah, bl.s, acc, 0, 0, 0);
                acc = __builtin_amdgcn_mfma_f32_16x16x32_bf16(al, bh.s, acc, 0, 0, 0);
            }
            float ig = 1.f / (1.f + expf(-acc[0]));
            float fg = 1.f / (1.f + expf(-acc[1]));
            float gg = tanhf(acc[2]);
            float og = 1.f / (1.f + expf(-acc[3]));
            c = fg * c + ig * gg;
            float h = og * tanhf(c);
            out[((size_t)t*1024 + dir*512 + kg)*64 + bb] = h;
            astore_u32(((u & 1) ? hp1 : hp0) + (size_t)bb*512 + kg, pack_split(h));
            if (s == TC-1) cbuf[(size_t)dir*32768 + (size_t)kg*64 + bb] = c;
            asm volatile("s_waitcnt vmcnt(0)" ::: "memory");
        }
        __syncthreads();   // publishes drained before any wave re-arrives
    }
}

// ---------------- emissions -----------------------------------------------------
__global__ __launch_bounds__(256) void emis_kernel(
    const float* __restrict__ h1, const float* __restrict__ Wout,
    const float* __restrict__ bout, float* __restrict__ em)
{
    const int s = blockIdx.x;
    const int tid = threadIdx.x;
    const int b = tid & 63;
    const int cl = tid >> 6;
    __shared__ float wl[32][128];
    float acc[8];
#pragma unroll
    for (int u = 0; u < 8; ++u) acc[u] = 0.f;
    const float* hp = h1 + (size_t)s * (1024*64);
    for (int f0 = 0; f0 < 1024; f0 += 128) {
        __syncthreads();
        for (int u = tid; u < 4096; u += 256) {
            int cc = u >> 7, ff = u & 127;
            wl[cc][ff] = Wout[(size_t)cc*1024 + f0 + ff];
        }
        __syncthreads();
        for (int ff = 0; ff < 128; ++ff) {
            float hv = hp[(size_t)(f0+ff)*64 + b];
#pragma unroll
            for (int u = 0; u < 8; ++u) acc[u] += hv * wl[cl + u*4][ff];
        }
    }
#pragma unroll
    for (int u = 0; u < 8; ++u) {
        int cc = cl + u*4;
        em[((size_t)b*T_ + s)*C_ + cc] = acc[u] + bout[cc];
    }
}

// ---------------- CRF Viterbi ---------------------------------------------------
__global__ __launch_bounds__(64) void viterbi_kernel(
    const float* __restrict__ em, const float* __restrict__ start_t,
    const float* __restrict__ end_t, const float* __restrict__ trans,
    float* __restrict__ dout)
{
    const int b = blockIdx.x;
    const int j = threadIdx.x;
    __shared__ float tr[C_*C_];
    __shared__ float sc[2][C_];
    __shared__ unsigned char hist[T_-1][C_];
    for (int i = j; i < C_*C_; i += 64) tr[i] = trans[i];
    const float* emb = em + (size_t)b * T_ * C_;
    if (j < C_) sc[0][j] = start_t[j] + emb[j];
    __syncthreads();
    for (int s = 1; s < T_; ++s) {
        int cur = (s-1) & 1, nxt = s & 1;
        if (j < C_) {
            float best = -3.4e38f; int bi = 0;
            for (int i = 0; i < C_; ++i) {
                float v = sc[cur][i] + tr[i*C_ + j];
                if (v > best) { best = v; bi = i; }
            }
            sc[nxt][j] = best + emb[(size_t)s*C_ + j];
            hist[s-1][j] = (unsigned char)bi;
        }
        __syncthreads();
    }
    if (j == 0) {
        const int cur = (T_-1) & 1;
        float best = -3.4e38f; int bi = 0;
        for (int i = 0; i < C_; ++i) {
            float v = sc[cur][i] + end_t[i];
            if (v > best) { best = v; bi = i; }
        }
        dout[(size_t)B_*T_ + b] = best;
        float* tout = dout + (size_t)b * T_;
        int tag = bi;
        tout[T_-1] = (float)tag;
        for (int s = T_-2; s >= 0; --s) {
            tag = hist[s][tag];
            tout[s] = (float)tag;
        }
    }
}

// ---------------- host launch ---------------------------------------------------
extern "C" void kernel_launch(void* const* d_in, const int* in_sizes, int n_in,
                              void* d_out, int out_size, void* d_ws, size_t ws_size,
                              hipStream_t stream) {
    const float* x    = (const float*)d_in[0];
    const float* Wih0 = (const float*)d_in[2];
    const float* Whh0 = (const float*)d_in[3];
    const float* b0   = (const float*)d_in[4];
    const float* Wih1 = (const float*)d_in[5];
    const float* Whh1 = (const float*)d_in[6];
    const float* b1   = (const float*)d_in[7];
    const float* Wout = (const float*)d_in[8];
    const float* bout = (const float*)d_in[9];
    const float* st   = (const float*)d_in[10];
    const float* en   = (const float*)d_in[11];
    const float* tr   = (const float*)d_in[12];
    float* dout = (float*)d_out;

    char* ws = (char*)d_ws;
    unsigned* bar  = (unsigned*)ws;                               // 4 KiB (8 ctrs, 128B apart)
    unsigned* hpk  = (unsigned*)(ws + 4096);                      // 512 KiB packed h
    float* cbuf = (float*)(ws + 4096 + 524288);                   // 256 KiB
    float* em   = (float*)(ws + 4096 + (1u << 20));               // 2 MiB
    float* h0   = (float*)(ws + 4096 + (1u << 20) + (2u << 20));  // 64 MiB
    float* h1   = h0 + (size_t)T_ * 1024 * B_;                    // 64 MiB
    float* pre  = h1 + (size_t)T_ * 1024 * B_;                    // 16.8 MiB

    hipMemsetAsync(bar, 0, 4096, stream);

    const int LDS_BYTES = 163840;   // 32K W split + 128K B packed
    hipFuncSetAttribute(reinterpret_cast<const void*>(lstm_scan),
                        hipFuncAttributeMaxDynamicSharedMemorySize, LDS_BYTES);

    dim3 bb(256);
    dim3 gg(NCOLS/128, 32);
    for (int ci = 0; ci < 16; ++ci) {
        int lo = ci * TC;
        gemm_f32<<<gg, bb, 0, stream>>>(Wih0, x, b0, pre, F0_, 0, lo);
        lstm_scan<<<256, 512, LDS_BYTES, stream>>>(Whh0, pre, h0, hpk, cbuf, bar,
                                                   lo, ci == 0 ? 1 : 0, (unsigned)(ci * TC * 32));
    }
    for (int ci = 0; ci < 16; ++ci) {
        int lo = ci * TC;
        gemm_f32<<<gg, bb, 0, stream>>>(Wih1, h0, b1, pre, 1024, 1, lo);
        lstm_scan<<<256, 512, LDS_BYTES, stream>>>(Whh1, pre, h1, hpk, cbuf, bar,
                                                   lo, ci == 0 ? 1 : 0, (unsigned)((16 + ci) * TC * 32));
    }
    emis_kernel<<<T_, bb, 0, stream>>>(h1, Wout, bout, em);
    viterbi_kernel<<<B_, 64, 0, stream>>>(em, st, en, tr, dout);
}

// Round 9
// 8048.105 us; speedup vs baseline: 2.5774x; 1.1675x over previous
//
#include <hip/hip_runtime.h>

#define B_   64
#define T_   256
#define H_   512
#define F0_  256
#define C_   32
#define TC   16
#define NCOLS (TC*64)   // 1024

typedef short short8 __attribute__((ext_vector_type(8)));
typedef float f32x4 __attribute__((ext_vector_type(4)));
typedef unsigned long long u64;

__device__ __forceinline__ unsigned aload_u32(const unsigned* p) {
    return __hip_atomic_load(p, __ATOMIC_RELAXED, __HIP_MEMORY_SCOPE_AGENT);
}
__device__ __forceinline__ void astore_u32(unsigned* p, unsigned v) {
    __hip_atomic_store(p, v, __ATOMIC_RELAXED, __HIP_MEMORY_SCOPE_AGENT);
}
__device__ __forceinline__ u64 aload_u64(const u64* p) {
    return __hip_atomic_load(p, __ATOMIC_RELAXED, __HIP_MEMORY_SCOPE_AGENT);
}

// split f32 -> (bf16 hi | bf16 lo) packed in u32 (hi in top 16, lo in bottom 16)
__device__ __forceinline__ unsigned pack_split(float x) {
    unsigned xb = __float_as_uint(x);
    unsigned hi = (xb + 0x7fffu + ((xb >> 16) & 1u)) & 0xffff0000u;
    float rest = x - __uint_as_float(hi);
    unsigned rb = __float_as_uint(rest);
    unsigned lo = (rb + 0x7fffu + ((rb >> 16) & 1u)) >> 16;
    return hi | (lo & 0xffffu);
}

// unpack 8 packed u32 (2x uint4) into hi-bf16x8 / lo-bf16x8 (r8-verified ordering)
__device__ __forceinline__ void unpack8(uint4 u0, uint4 u1, short8& hi, short8& lo) {
    union { uint4 u; short8 s; } H, L;
    H.u = make_uint4((u0.x >> 16) | (u0.y & 0xffff0000u),
                     (u0.z >> 16) | (u0.w & 0xffff0000u),
                     (u1.x >> 16) | (u1.y & 0xffff0000u),
                     (u1.z >> 16) | (u1.w & 0xffff0000u));
    L.u = make_uint4((u0.x & 0xffffu) | (u0.y << 16),
                     (u0.z & 0xffffu) | (u0.w << 16),
                     (u1.x & 0xffffu) | (u1.y << 16),
                     (u1.z & 0xffffu) | (u1.w << 16));
    hi = H.s; lo = L.s;
}

// ---------------- elementwise f32 -> packed split u32 ---------------------------
__global__ __launch_bounds__(256) void pack_kernel(
    const float* __restrict__ in, unsigned* __restrict__ out, int n)
{
    for (int i = blockIdx.x*256 + threadIdx.x; i < n; i += gridDim.x*256)
        out[i] = pack_split(in[i]);
}

// ---------------- MFMA split-bf16 GEMM: pre(4096, NCOLS) = W * B^T + bias ------
// 128x128 tile, 256 threads = 4 waves (wave quadrant 64x64, 4x4 acc tiles).
// A: W packed u32 [m][K] (Wpk, or packed in-register from Wf if Wpk==null).
// B: mode 0 = x (B_,T_,F0_) f32; mode 1 = h0 (T_,1024,B_) f32 -> packed in-stage.
// LDS: As/Bs 128x32 u32 with 16B-chunk XOR swizzle (row&7). 3-product split.
__global__ __launch_bounds__(256) void gemm_mfma(
    const unsigned* __restrict__ Wpk, const float* __restrict__ Wf,
    const float* __restrict__ Bsrc, const float* __restrict__ bias,
    float* __restrict__ Cout, int K, int mode, int lo)
{
    __shared__ __align__(16) unsigned As[4096];
    __shared__ __align__(16) unsigned Bs[4096];
    char* asb = (char*)As; char* bsb = (char*)Bs;
    const int m0 = blockIdx.y * 128;
    const int n0 = blockIdx.x * 128;
    const int dir = m0 >> 11;
    const int tid = threadIdx.x;
    const int w = tid >> 6;
    const int lane = tid & 63;
    const int dlt = lane & 15, gma = lane >> 4;
    const int mw = (w >> 1) * 64, nw = (w & 1) * 64;
    const int srow = tid >> 1;      // staging row 0..127
    const int sh   = tid & 1;       // staging half (k-offset sh*16)

    f32x4 acc[4][4];
#pragma unroll
    for (int mi = 0; mi < 4; ++mi)
#pragma unroll
        for (int ni = 0; ni < 4; ++ni) acc[mi][ni] = (f32x4){0.f,0.f,0.f,0.f};

    for (int k0 = 0; k0 < K; k0 += 32) {
        __syncthreads();
        {   // ---- A tile: 128 m x 32 k packed ----
            unsigned v[16];
            if (Wpk) {
                const unsigned* ap = Wpk + (size_t)(m0 + srow)*K + k0 + sh*16;
                uint4 q0 = *(const uint4*)(ap);
                uint4 q1 = *(const uint4*)(ap + 4);
                uint4 q2 = *(const uint4*)(ap + 8);
                uint4 q3 = *(const uint4*)(ap + 12);
                v[0]=q0.x; v[1]=q0.y; v[2]=q0.z; v[3]=q0.w;
                v[4]=q1.x; v[5]=q1.y; v[6]=q1.z; v[7]=q1.w;
                v[8]=q2.x; v[9]=q2.y; v[10]=q2.z; v[11]=q2.w;
                v[12]=q3.x; v[13]=q3.y; v[14]=q3.z; v[15]=q3.w;
            } else {
                const float* ap = Wf + (size_t)(m0 + srow)*K + k0 + sh*16;
#pragma unroll
                for (int i = 0; i < 16; ++i) v[i] = pack_split(ap[i]);
            }
#pragma unroll
            for (int j = 0; j < 4; ++j) {
                int c = sh*4 + j;
                int byte = srow*128 + ((c ^ (srow & 7)) << 4);
                *(uint4*)(asb + byte) = make_uint4(v[4*j],v[4*j+1],v[4*j+2],v[4*j+3]);
            }
        }
        {   // ---- B tile: 128 n x 32 k, pack f32 in-register ----
            const int n = n0 + srow;
            const int bb2 = n & 63, tloc = n >> 6;
            const int t = dir ? (255 - lo - tloc) : (lo + tloc);
            unsigned v[16];
            if (mode == 0) {
                const float* bp = Bsrc + ((size_t)bb2*T_ + t)*F0_ + k0 + sh*16;
#pragma unroll
                for (int i = 0; i < 16; ++i) v[i] = pack_split(bp[i]);
            } else {
                const float* bp = Bsrc + (size_t)t*(1024*64) + (size_t)(k0 + sh*16)*64 + bb2;
#pragma unroll
                for (int i = 0; i < 16; ++i) v[i] = pack_split(bp[(size_t)i*64]);
            }
#pragma unroll
            for (int j = 0; j < 4; ++j) {
                int c = sh*4 + j;
                int byte = srow*128 + ((c ^ (srow & 7)) << 4);
                *(uint4*)(bsb + byte) = make_uint4(v[4*j],v[4*j+1],v[4*j+2],v[4*j+3]);
            }
        }
        __syncthreads();

        // ---- mfma: 4x4 tiles, 3 products each ----
        short8 ah[4], al[4];
#pragma unroll
        for (int mi = 0; mi < 4; ++mi) {
            int base = (mw + mi*16 + dlt) * 128;
            uint4 u0 = *(const uint4*)(asb + base + (((gma*2    ) ^ (dlt & 7)) << 4));
            uint4 u1 = *(const uint4*)(asb + base + (((gma*2 + 1) ^ (dlt & 7)) << 4));
            unpack8(u0, u1, ah[mi], al[mi]);
        }
#pragma unroll
        for (int ni = 0; ni < 4; ++ni) {
            int base = (nw + ni*16 + dlt) * 128;
            uint4 u0 = *(const uint4*)(bsb + base + (((gma*2    ) ^ (dlt & 7)) << 4));
            uint4 u1 = *(const uint4*)(bsb + base + (((gma*2 + 1) ^ (dlt & 7)) << 4));
            short8 bh, bl;
            unpack8(u0, u1, bh, bl);
#pragma unroll
            for (int mi = 0; mi < 4; ++mi) {
                acc[mi][ni] = __builtin_amdgcn_mfma_f32_16x16x32_bf16(ah[mi], bh, acc[mi][ni], 0, 0, 0);
                acc[mi][ni] = __builtin_amdgcn_mfma_f32_16x16x32_bf16(ah[mi], bl, acc[mi][ni], 0, 0, 0);
                acc[mi][ni] = __builtin_amdgcn_mfma_f32_16x16x32_bf16(al[mi], bh, acc[mi][ni], 0, 0, 0);
            }
        }
    }

    // ---- epilogue: C layout col = lane&15, row = (lane>>4)*4 + r (m89) ----
#pragma unroll
    for (int mi = 0; mi < 4; ++mi)
#pragma unroll
        for (int ni = 0; ni < 4; ++ni) {
            const int n = n0 + nw + ni*16 + dlt;
#pragma unroll
            for (int r = 0; r < 4; ++r) {
                const int m = m0 + mw + mi*16 + gma*4 + r;
                Cout[(size_t)m*NCOLS + n] = acc[mi][ni][r] + bias[m];
            }
        }
}

// ---------------- persistent bidirectional LSTM scan, MFMA split-bf16 ----------
// (unchanged from round 8 — 204 us/chunk, absmax 0.0)
#define LDS_W_HI 0
#define LDS_W_LO 16384
#define LDS_B    32768

__global__ __launch_bounds__(512, 1) void lstm_scan(
    const float* __restrict__ Whh,   // (2, 2048, 512)
    const float* __restrict__ pre,   // (4096, NCOLS)
    float* __restrict__ out,         // (T_, 1024, B_)
    unsigned* __restrict__ hpk,      // [2 par][2 dir][64 b][512 k] packed u32
    float* __restrict__ cbuf,        // [2 dir][512 k][64 b]
    unsigned* bar,
    int lo, int first, unsigned tgt0)
{
    extern __shared__ char smem[];
    const int bid  = blockIdx.x;
    const int dir  = bid >> 7;
    const int kblk = bid & 127;
    const int tid  = threadIdx.x;
    const int wid  = tid >> 6;
    const int lane = tid & 63;
    const int dlt  = lane & 15;
    const int gma  = lane >> 4;

    {   // W prep: A row m = kl*4+g
        const int m  = tid >> 5;
        const int j0 = (tid & 31) * 16;
        const int g = m & 3, kl = m >> 2;
        const float* wr = Whh + ((size_t)(dir*2048 + g*512 + kblk*4 + kl))*512 + j0;
        unsigned hw[8], lw[8];
#pragma unroll
        for (int i = 0; i < 8; ++i) {
            unsigned q0 = pack_split(wr[2*i]);
            unsigned q1 = pack_split(wr[2*i+1]);
            hw[i] = (q0 >> 16) | (q1 & 0xffff0000u);
            lw[i] = (q0 & 0xffffu) | (q1 << 16);
        }
        const int jb = j0 * 2;
        const int of0 = (m << 10) + ((jb     ) ^ ((m & 7) << 4));
        const int of1 = (m << 10) + ((jb + 16) ^ ((m & 7) << 4));
        *(uint4*)(smem + LDS_W_HI + of0) = make_uint4(hw[0],hw[1],hw[2],hw[3]);
        *(uint4*)(smem + LDS_W_HI + of1) = make_uint4(hw[4],hw[5],hw[6],hw[7]);
        *(uint4*)(smem + LDS_W_LO + of0) = make_uint4(lw[0],lw[1],lw[2],lw[3]);
        *(uint4*)(smem + LDS_W_LO + of1) = make_uint4(lw[4],lw[5],lw[6],lw[7]);
    }

    unsigned* hp0 = hpk + (size_t)(0*2 + dir) * 32768;
    unsigned* hp1 = hpk + (size_t)(1*2 + dir) * 32768;

    const int kg = kblk*4 + gma;
    const int bb = wid*16 + dlt;

    float c = 0.f;
    if (first) {
        for (int i = tid; i < 32768; i += 512) astore_u32(&hp1[i], 0u);
    } else if (wid < 4) {
        c = cbuf[(size_t)dir*32768 + (size_t)kg*64 + bb];
    }
    asm volatile("s_waitcnt vmcnt(0)" ::: "memory");
    __syncthreads();

    const int mycnt = (bid & 7) * 32;
    unsigned target = tgt0;
    const int bof0 = (2*gma)*1024 + ((bb ^ (2*gma)) << 4);
    const int bof1 = (2*gma+1)*1024 + ((bb ^ (2*gma+1)) << 4);

    for (int s = 0; s < TC; ++s) {
        const int u = lo + s;
        const int t = dir ? (255 - u) : u;

        float p0, p1, p2, p3;
        if (wid < 4) {
            const size_t col = (size_t)s*64 + bb;
            p0 = pre[((size_t)(dir*2048 +        kg))*NCOLS + col];
            p1 = pre[((size_t)(dir*2048 +  512 + kg))*NCOLS + col];
            p2 = pre[((size_t)(dir*2048 + 1024 + kg))*NCOLS + col];
            p3 = pre[((size_t)(dir*2048 + 1536 + kg))*NCOLS + col];
        }

        if (tid == 0)
            __hip_atomic_fetch_add(&bar[mycnt], 1u, __ATOMIC_RELAXED, __HIP_MEMORY_SCOPE_AGENT);
        target += 32;
        if (tid < 8) {
            while (__hip_atomic_load(&bar[tid*32], __ATOMIC_RELAXED, __HIP_MEMORY_SCOPE_AGENT) < target)
                __builtin_amdgcn_s_sleep(2);
        }
        __syncthreads();

        const u64* src64 = (const u64*)(((u + 1) & 1) ? hp1 : hp0);
#pragma unroll 8
        for (int it = 0; it < 32; ++it) {
            const int idx = it*512 + tid;
            u64 v = aload_u64(&src64[idx]);
            const int b  = idx >> 8;
            const int j2 = idx & 255;
            const int jc = j2 >> 1;
            const int byte = ((jc*64 + (b ^ (jc & 7))) << 4) + ((j2 & 1) << 3);
            *(u64*)(smem + LDS_B + byte) = v;
        }
        __syncthreads();

        if (wid < 4) {
            f32x4 acc = {p0, p1, p2, p3};
#pragma unroll
            for (int kt = 0; kt < 16; ++kt) {
                const int jb  = (kt << 6) + (gma << 4);
                const int aof = (dlt << 10) + (jb ^ ((dlt & 7) << 4));
                short8 ah = *(const short8*)(smem + LDS_W_HI + aof);
                short8 al = *(const short8*)(smem + LDS_W_LO + aof);
                uint4 u0 = *(const uint4*)(smem + LDS_B + bof0 + (kt << 13));
                uint4 u1 = *(const uint4*)(smem + LDS_B + bof1 + (kt << 13));
                short8 bh, bl;
                unpack8(u0, u1, bh, bl);
                acc = __builtin_amdgcn_mfma_f32_16x16x32_bf16(ah, bh, acc, 0, 0, 0);
                acc = __builtin_amdgcn_mfma_f32_16x16x32_bf16(ah, bl, acc, 0, 0, 0);
                acc = __builtin_amdgcn_mfma_f32_16x16x32_bf16(al, bh, acc, 0, 0, 0);
            }
            float ig = 1.f / (1.f + expf(-acc[0]));
            float fg = 1.f / (1.f + expf(-acc[1]));
            float gg = tanhf(acc[2]);
            float og = 1.f / (1.f + expf(-acc[3]));
            c = fg * c + ig * gg;
            float h = og * tanhf(c);
            out[((size_t)t*1024 + dir*512 + kg)*64 + bb] = h;
            astore_u32(((u & 1) ? hp1 : hp0) + (size_t)bb*512 + kg, pack_split(h));
            if (s == TC-1) cbuf[(size_t)dir*32768 + (size_t)kg*64 + bb] = c;
            asm volatile("s_waitcnt vmcnt(0)" ::: "memory");
        }
        __syncthreads();
    }
}

// ---------------- emissions -----------------------------------------------------
__global__ __launch_bounds__(256) void emis_kernel(
    const float* __restrict__ h1, const float* __restrict__ Wout,
    const float* __restrict__ bout, float* __restrict__ em)
{
    const int s = blockIdx.x;
    const int tid = threadIdx.x;
    const int b = tid & 63;
    const int cl = tid >> 6;
    __shared__ float wl[32][128];
    float acc[8];
#pragma unroll
    for (int u = 0; u < 8; ++u) acc[u] = 0.f;
    const float* hp = h1 + (size_t)s * (1024*64);
    for (int f0 = 0; f0 < 1024; f0 += 128) {
        __syncthreads();
        for (int u = tid; u < 4096; u += 256) {
            int cc = u >> 7, ff = u & 127;
            wl[cc][ff] = Wout[(size_t)cc*1024 + f0 + ff];
        }
        __syncthreads();
        for (int ff = 0; ff < 128; ++ff) {
            float hv = hp[(size_t)(f0+ff)*64 + b];
#pragma unroll
            for (int u = 0; u < 8; ++u) acc[u] += hv * wl[cl + u*4][ff];
        }
    }
#pragma unroll
    for (int u = 0; u < 8; ++u) {
        int cc = cl + u*4;
        em[((size_t)b*T_ + s)*C_ + cc] = acc[u] + bout[cc];
    }
}

// ---------------- CRF Viterbi ---------------------------------------------------
__global__ __launch_bounds__(64) void viterbi_kernel(
    const float* __restrict__ em, const float* __restrict__ start_t,
    const float* __restrict__ end_t, const float* __restrict__ trans,
    float* __restrict__ dout)
{
    const int b = blockIdx.x;
    const int j = threadIdx.x;
    __shared__ float tr[C_*C_];
    __shared__ float sc[2][C_];
    __shared__ unsigned char hist[T_-1][C_];
    for (int i = j; i < C_*C_; i += 64) tr[i] = trans[i];
    const float* emb = em + (size_t)b * T_ * C_;
    if (j < C_) sc[0][j] = start_t[j] + emb[j];
    __syncthreads();
    for (int s = 1; s < T_; ++s) {
        int cur = (s-1) & 1, nxt = s & 1;
        if (j < C_) {
            float best = -3.4e38f; int bi = 0;
            for (int i = 0; i < C_; ++i) {
                float v = sc[cur][i] + tr[i*C_ + j];
                if (v > best) { best = v; bi = i; }
            }
            sc[nxt][j] = best + emb[(size_t)s*C_ + j];
            hist[s-1][j] = (unsigned char)bi;
        }
        __syncthreads();
    }
    if (j == 0) {
        const int cur = (T_-1) & 1;
        float best = -3.4e38f; int bi = 0;
        for (int i = 0; i < C_; ++i) {
            float v = sc[cur][i] + end_t[i];
            if (v > best) { best = v; bi = i; }
        }
        dout[(size_t)B_*T_ + b] = best;
        float* tout = dout + (size_t)b * T_;
        int tag = bi;
        tout[T_-1] = (float)tag;
        for (int s = T_-2; s >= 0; --s) {
            tag = hist[s][tag];
            tout[s] = (float)tag;
        }
    }
}

// ---------------- host launch ---------------------------------------------------
extern "C" void kernel_launch(void* const* d_in, const int* in_sizes, int n_in,
                              void* d_out, int out_size, void* d_ws, size_t ws_size,
                              hipStream_t stream) {
    const float* x    = (const float*)d_in[0];
    const float* Wih0 = (const float*)d_in[2];
    const float* Whh0 = (const float*)d_in[3];
    const float* b0   = (const float*)d_in[4];
    const float* Wih1 = (const float*)d_in[5];
    const float* Whh1 = (const float*)d_in[6];
    const float* b1   = (const float*)d_in[7];
    const float* Wout = (const float*)d_in[8];
    const float* bout = (const float*)d_in[9];
    const float* st   = (const float*)d_in[10];
    const float* en   = (const float*)d_in[11];
    const float* tr   = (const float*)d_in[12];
    float* dout = (float*)d_out;

    char* ws = (char*)d_ws;
    const size_t o_bar  = 0;                                  // 4 KiB
    const size_t o_hpk  = 4096;                               // 512 KiB
    const size_t o_cbuf = o_hpk + 524288;                     // 256 KiB
    const size_t o_em   = o_cbuf + 262144;                    // 2 MiB
    const size_t o_h0   = o_em + 2097152;                     // 64 MiB
    const size_t o_h1   = o_h0 + (size_t)67108864;            // 64 MiB
    const size_t o_pre  = o_h1 + (size_t)67108864;            // 16 MiB
    const size_t o_w0pk = o_pre + (size_t)16777216;           // 4 MiB
    const size_t o_w1pk = o_w0pk + (size_t)4194304;           // 16 MiB
    const size_t need_packed = o_w1pk + (size_t)16777216;     // ~167 MiB

    unsigned* bar  = (unsigned*)(ws + o_bar);
    unsigned* hpk  = (unsigned*)(ws + o_hpk);
    float* cbuf = (float*)(ws + o_cbuf);
    float* em   = (float*)(ws + o_em);
    float* h0   = (float*)(ws + o_h0);
    float* h1   = (float*)(ws + o_h1);
    float* pre  = (float*)(ws + o_pre);
    const bool packW = (ws_size >= need_packed);
    unsigned* w0pk = packW ? (unsigned*)(ws + o_w0pk) : nullptr;
    unsigned* w1pk = packW ? (unsigned*)(ws + o_w1pk) : nullptr;

    hipMemsetAsync(bar, 0, 4096, stream);

    const int LDS_BYTES = 163840;
    hipFuncSetAttribute(reinterpret_cast<const void*>(lstm_scan),
                        hipFuncAttributeMaxDynamicSharedMemorySize, LDS_BYTES);

    if (packW) {
        pack_kernel<<<1024, 256, 0, stream>>>(Wih0, w0pk, 4096*256);
        pack_kernel<<<2048, 256, 0, stream>>>(Wih1, w1pk, 4096*1024);
    }

    dim3 gg(NCOLS/128, 32), bb(256);
    for (int ci = 0; ci < 16; ++ci) {
        int lo = ci * TC;
        gemm_mfma<<<gg, bb, 0, stream>>>(w0pk, Wih0, x, b0, pre, F0_, 0, lo);
        lstm_scan<<<256, 512, LDS_BYTES, stream>>>(Whh0, pre, h0, hpk, cbuf, bar,
                                                   lo, ci == 0 ? 1 : 0, (unsigned)(ci * TC * 32));
    }
    for (int ci = 0; ci < 16; ++ci) {
        int lo = ci * TC;
        gemm_mfma<<<gg, bb, 0, stream>>>(w1pk, Wih1, h0, b1, pre, 1024, 1, lo);
        lstm_scan<<<256, 512, LDS_BYTES, stream>>>(Whh1, pre, h1, hpk, cbuf, bar,
                                                   lo, ci == 0 ? 1 : 0, (unsigned)((16 + ci) * TC * 32));
    }
    emis_kernel<<<T_, bb, 0, stream>>>(h1, Wout, bout, em);
    viterbi_kernel<<<B_, 64, 0, stream>>>(em, st, en, tr, dout);
}